// Round 19
// baseline (99.516 us; speedup 1.0000x reference)
//
#include <hip/hip_runtime.h>
#include <hip/hip_bf16.h>
#include <math.h>

#define TT    1024   // B*S tokens
#define DD    768    // hidden dim
#define NHEAD 12
#define HDIM  64
#define NBLK  16
#define NMID  14
#define NCOUT 16

typedef __attribute__((ext_vector_type(4))) float f32x4;
typedef __attribute__((ext_vector_type(8))) short bfrag;   // 8 bf16 = 4 VGPRs

#define MFMA(a, b, c) __builtin_amdgcn_mfma_f32_16x16x32_bf16(a, b, c, 0, 0, 0)

__device__ __forceinline__ bfrag ldg8(const ushort* p) { return *(const bfrag*)p; }
__device__ __forceinline__ ushort f2bf(float f) {
    __hip_bfloat16 h = __float2bfloat16(f);
    return *(ushort*)&h;
}

// ---------------------------------------------------------------------------
// Fused prep: blocks [0,768) convert X fp32->bf16; blocks [768, 768+2880)
// transpose+convert the 5 weight matrices W[k][n] -> WT[n][k] bf16.
// ---------------------------------------------------------------------------
__global__ __launch_bounds__(256) void prep_k(
    const float* __restrict__ X,
    const float* __restrict__ Wq, const float* __restrict__ Wk,
    const float* __restrict__ Wv, const float* __restrict__ Wo,
    const float* __restrict__ Wd,
    ushort* __restrict__ xb,
    ushort* __restrict__ qT, ushort* __restrict__ kT, ushort* __restrict__ vT,
    ushort* __restrict__ oT, ushort* __restrict__ dT)
{
    __shared__ float t[32][33];
    int bx = blockIdx.x;
    if (bx < 768) {                                  // X conversion
        int i = bx * 256 + threadIdx.x;              // float4 index
        float4 f = ((const float4*)X)[i];
        ushort4 u;
        u.x = f2bf(f.x); u.y = f2bf(f.y); u.z = f2bf(f.z); u.w = f2bf(f.w);
        ((ushort4*)xb)[i] = u;
        return;
    }
    int bz = bx - 768;                               // 0..2879
    int z = bz / 576;
    int rem = bz % 576;
    int k0 = (rem / 24) * 32, n0 = (rem % 24) * 32;
    const float* W; ushort* O;
    if (z == 0)      { W = Wq; O = qT; }
    else if (z == 1) { W = Wk; O = kT; }
    else if (z == 2) { W = Wv; O = vT; }
    else if (z == 3) { W = Wo; O = oT; }
    else             { W = Wd; O = dT; }
    int tx = threadIdx.x & 31, ty = threadIdx.x >> 5;   // ty 0..7
    #pragma unroll
    for (int i = 0; i < 4; i++)
        t[ty + i * 8][tx] = W[(k0 + ty + i * 8) * DD + n0 + tx];
    __syncthreads();
    #pragma unroll
    for (int i = 0; i < 4; i++)
        O[(n0 + ty + i * 8) * DD + k0 + tx] = f2bf(t[tx][ty + i * 8]);
}

// ---------------------------------------------------------------------------
// QKV MFMA GEMM, K-split, 64-row tiles (R13): grid (16, 12, 3).
// ---------------------------------------------------------------------------
__global__ __launch_bounds__(256) void qkv_mfma_k(
    const ushort* __restrict__ xb,
    const ushort* __restrict__ wqT, const ushort* __restrict__ wkT,
    const ushort* __restrict__ wvT,
    const float* __restrict__ bq, const float* __restrict__ bk,
    const float* __restrict__ bv,
    ushort* __restrict__ qo, ushort* __restrict__ ko, ushort* __restrict__ vTo)
{
    int z = blockIdx.z;
    const ushort* BT = (z == 0) ? wqT : (z == 1) ? wkT : wvT;
    const float* bias = (z == 0) ? bq : (z == 1) ? bk : bv;

    __shared__ float mo[4][16][4][64];   // [wave][m*4+nt][j][lane] = 64KB
    int lane = threadIdx.x & 63, w = threadIdx.x >> 6;
    int lr = lane & 15, lg = lane >> 4;
    int row0 = blockIdx.x * 64;
    int h = blockIdx.y;
    int col0 = h * 64;

    f32x4 acc[16];
    #pragma unroll
    for (int p = 0; p < 16; p++) acc[p] = (f32x4){0, 0, 0, 0};
    const ushort* ap = xb + (size_t)(row0 + lr) * DD + w * 192 + lg * 8;
    const ushort* bp = BT + (size_t)(col0 + lr) * DD + w * 192 + lg * 8;
    #pragma unroll
    for (int ks = 0; ks < 6; ks++) {
        bfrag a0 = ldg8(ap + ks * 32);
        bfrag a1 = ldg8(ap + (size_t)16 * DD + ks * 32);
        bfrag a2 = ldg8(ap + (size_t)32 * DD + ks * 32);
        bfrag a3 = ldg8(ap + (size_t)48 * DD + ks * 32);
        #pragma unroll
        for (int nt = 0; nt < 4; nt++) {
            bfrag b = ldg8(bp + (size_t)nt * 16 * DD + ks * 32);
            acc[nt]      = MFMA(a0, b, acc[nt]);
            acc[4 + nt]  = MFMA(a1, b, acc[4 + nt]);
            acc[8 + nt]  = MFMA(a2, b, acc[8 + nt]);
            acc[12 + nt] = MFMA(a3, b, acc[12 + nt]);
        }
    }
    #pragma unroll
    for (int p = 0; p < 16; p++)
        #pragma unroll
        for (int j = 0; j < 4; j++)
            mo[w][p][j][lane] = acc[p][j];
    __syncthreads();

    // wave w merges fragments p = w + 4*pi (pi 0..3)
    #pragma unroll
    for (int pi = 0; pi < 4; pi++) {
        int p = w + pi * 4;
        int m = p >> 2, nt = p & 3;
        #pragma unroll
        for (int j = 0; j < 4; j++) {
            float of = mo[0][p][j][lane] + mo[1][p][j][lane] +
                       mo[2][p][j][lane] + mo[3][p][j][lane];
            int r = row0 + m * 16 + lg * 4 + j;
            int cc = nt * 16 + lr;                 // col within head
            ushort u = f2bf(of + bias[col0 + cc]);
            if (z == 2)      vTo[(size_t)(h * 64 + cc) * TT + r] = u;
            else if (z == 0) qo[(size_t)(h * TT + r) * 64 + cc] = u;
            else             ko[(size_t)(h * TT + r) * 64 + cc] = u;
        }
    }
}

// ---------------------------------------------------------------------------
// Generic MFMA GEMM, K-split, 32-row tiles (R11-proven): grid (32,12).
// OUTF32=0 -> bf16 out, OUTF32=1 -> f32 out.
// ---------------------------------------------------------------------------
template <int OUTF32>
__global__ __launch_bounds__(256) void mm_mfma_k(
    const ushort* __restrict__ A, const ushort* __restrict__ BT,
    const float* __restrict__ bias, void* __restrict__ out)
{
    __shared__ float mo[4][8][4][64];   // [wave][m*4+nt][j][lane] = 32KB
    int lane = threadIdx.x & 63, w = threadIdx.x >> 6;
    int lr = lane & 15, lg = lane >> 4;
    int row0 = blockIdx.x * 32;
    int col0 = blockIdx.y * 64;

    f32x4 acc[8];
    #pragma unroll
    for (int p = 0; p < 8; p++) acc[p] = (f32x4){0, 0, 0, 0};
    const ushort* a0p = A + (size_t)(row0 + lr) * DD + w * 192 + lg * 8;
    const ushort* a1p = a0p + (size_t)16 * DD;
    const ushort* bp  = BT + (size_t)(col0 + lr) * DD + w * 192 + lg * 8;
    #pragma unroll
    for (int ks = 0; ks < 6; ks++) {
        bfrag a0 = ldg8(a0p + ks * 32);
        bfrag a1 = ldg8(a1p + ks * 32);
        #pragma unroll
        for (int nt = 0; nt < 4; nt++) {
            bfrag b = ldg8(bp + (size_t)nt * 16 * DD + ks * 32);
            acc[nt]     = MFMA(a0, b, acc[nt]);
            acc[4 + nt] = MFMA(a1, b, acc[4 + nt]);
        }
    }
    #pragma unroll
    for (int p = 0; p < 8; p++)
        #pragma unroll
        for (int j = 0; j < 4; j++)
            mo[w][p][j][lane] = acc[p][j];
    __syncthreads();

    // wave w merges fragment pairs p = w and p = w+4
    #pragma unroll
    for (int pi = 0; pi < 2; pi++) {
        int p = w + pi * 4;
        int m = p >> 2, nt = p & 3;
        #pragma unroll
        for (int j = 0; j < 4; j++) {
            float of = mo[0][p][j][lane] + mo[1][p][j][lane] +
                       mo[2][p][j][lane] + mo[3][p][j][lane];
            int r = row0 + m * 16 + lg * 4 + j;
            int c = col0 + nt * 16 + lr;
            float v = of + bias[c];
            if (OUTF32) ((float*)out)[(size_t)r * DD + c] = v;
            else        ((ushort*)out)[(size_t)r * DD + c] = f2bf(v);
        }
    }
}

// ---------------------------------------------------------------------------
// Attention wave cores.
// core2x2: 2 q-frags (32 rows) x 2 key blocks — mid path (R12-proven).
// core2:   1 q-frag (16 rows) x 2 key blocks — glob path.
// P strips per wave: core2x2 uses [0,4096) ushorts; core2 uses [0,2048).
// ---------------------------------------------------------------------------
__device__ __forceinline__ void attn_core2x2(
    const ushort* __restrict__ kbf, const ushort* __restrict__ vT,
    const int* __restrict__ mask, const int kblk[2], int h,
    bfrag aq0, bfrag aq1, bfrag aq2, bfrag aq3, ushort* __restrict__ Pw,
    f32x4 (&o0)[4], f32x4 (&o1)[4], float (&l0)[4], float (&l1)[4])
{
    int lane = threadIdx.x & 63, lr = lane & 15, lg = lane >> 4;
    #pragma unroll
    for (int kb = 0; kb < 2; kb++) {
        int bi = kblk[kb];
        #pragma unroll
        for (int kt = 0; kt < 4; kt++) {
            int key = bi * 64 + kt * 16 + lr;
            const ushort* krow = kbf + (size_t)(h * TT + key) * 64 + lg * 8;
            bfrag b0 = ldg8(krow);
            bfrag b1 = ldg8(krow + 32);
            f32x4 s0 = {0, 0, 0, 0}, s1 = {0, 0, 0, 0};
            s0 = MFMA(aq0, b0, s0); s0 = MFMA(aq1, b1, s0);
            s1 = MFMA(aq2, b0, s1); s1 = MFMA(aq3, b1, s1);
            int mk = mask[key];
            #pragma unroll
            for (int j = 0; j < 4; j++) {
                int row = lg * 4 + j;
                int base = (row * 128 + (kb * 4 + kt) * 16 + lr)
                           ^ ((row & 7) << 3);
                float p0 = (mk > 0) ? __expf(s0[j] * 0.125f) : 0.0f;
                l0[j] += p0;
                Pw[base] = f2bf(p0);
                float p1 = (mk > 0) ? __expf(s1[j] * 0.125f) : 0.0f;
                l1[j] += p1;
                Pw[2048 + base] = f2bf(p1);
            }
        }
    }
    #pragma unroll
    for (int ks = 0; ks < 4; ks++) {           // 32-key chunks
        int bi = kblk[ks >> 1];
        int pidx = (lr * 128 + ks * 32 + lg * 8) ^ ((lr & 7) << 3);
        bfrag pa0 = *(const bfrag*)(Pw + pidx);
        bfrag pa1 = *(const bfrag*)(Pw + 2048 + pidx);
        #pragma unroll
        for (int dt = 0; dt < 4; dt++) {
            const ushort* vrow = vT + (size_t)(h * 64 + dt * 16 + lr) * TT
                               + bi * 64 + (ks & 1) * 32 + lg * 8;
            bfrag vv = ldg8(vrow);
            o0[dt] = MFMA(pa0, vv, o0[dt]);
            o1[dt] = MFMA(pa1, vv, o1[dt]);
        }
    }
}

__device__ __forceinline__ void attn_core2(
    const ushort* __restrict__ kbf, const ushort* __restrict__ vT,
    const int* __restrict__ mask, const int kblk[2], int h,
    bfrag aq0, bfrag aq1, ushort* __restrict__ Pw,
    f32x4 (&o)[4], float (&lsum)[4])
{
    int lane = threadIdx.x & 63, lr = lane & 15, lg = lane >> 4;
    #pragma unroll
    for (int kb = 0; kb < 2; kb++) {
        int bi = kblk[kb];
        #pragma unroll
        for (int kt = 0; kt < 4; kt++) {
            int key = bi * 64 + kt * 16 + lr;
            const ushort* krow = kbf + (size_t)(h * TT + key) * 64 + lg * 8;
            bfrag b0 = ldg8(krow);
            bfrag b1 = ldg8(krow + 32);
            f32x4 s = {0, 0, 0, 0};
            s = MFMA(aq0, b0, s);
            s = MFMA(aq1, b1, s);
            int mk = mask[key];
            #pragma unroll
            for (int j = 0; j < 4; j++) {
                int row = lg * 4 + j;
                int idx = (row * 128 + (kb * 4 + kt) * 16 + lr)
                          ^ ((row & 7) << 3);
                float pv = (mk > 0) ? __expf(s[j] * 0.125f) : 0.0f;
                lsum[j] += pv;
                Pw[idx] = f2bf(pv);
            }
        }
    }
    #pragma unroll
    for (int ks = 0; ks < 4; ks++) {           // 32-key chunks
        int bi = kblk[ks >> 1];
        int pidx = (lr * 128 + ks * 32 + lg * 8) ^ ((lr & 7) << 3);
        bfrag pa = *(const bfrag*)(Pw + pidx);
        #pragma unroll
        for (int dt = 0; dt < 4; dt++) {
            const ushort* vrow = vT + (size_t)(h * 64 + dt * 16 + lr) * TT
                               + bi * 64 + (ks & 1) * 32 + lg * 8;
            o[dt] = MFMA(pa, ldg8(vrow), o[dt]);
        }
    }
}

// ---------------------------------------------------------------------------
// Attention, k-split across waves, LOAD-BALANCED with COMPLETE-ROW blocks.
// Grid (36, 12):
//   x<28 : mid, 32 q-rows (qb = 1+(x>>1), half x&1), 8 gathered key blocks,
//          wave w covers 2 of them (core2x2, 2 q-frags).
//   x>=28: glob, 16 q-rows (g = (x-28)>>2, sub = (x-28)&3), ALL 16 key
//          blocks; wave w covers kb 4w..4w+3 via 2 core2 calls (1 q-frag).
// Work per block identical (256 MFMA); every block owns complete rows ->
// normalize + write ctx directly. No partials, no combine kernel.
// ---------------------------------------------------------------------------
__global__ __launch_bounds__(256, 3) void attn_k(
    const ushort* __restrict__ qbf, const ushort* __restrict__ kbf,
    const ushort* __restrict__ vT, const int* __restrict__ mask,
    const int* __restrict__ rnd, ushort* __restrict__ ctx)
{
    __shared__ __align__(16) ushort P[4][4096];   // 32KB (2 frags per wave)
    __shared__ float mo[4][4][4][64];             // 16KB (reused per frag)
    __shared__ float ml[4][16];
    int x = blockIdx.x, h = blockIdx.y;
    int w = threadIdx.x >> 6, lane = threadIdx.x & 63;
    int lr = lane & 15, lg = lane >> 4;

    bool isMid = (x < 28);
    int qtok0;
    if (isMid) {
        int qb = 1 + (x >> 1);
        qtok0 = qb * 64 + (x & 1) * 32;
    } else {
        int r = x - 28;               // 0..7
        int g = r >> 2;               // 0: qb0, 1: qb15
        int sub = r & 3;              // 16-row quarter of the 64-row block
        qtok0 = (g ? (NBLK - 1) : 0) * 64 + sub * 16;
    }

    const ushort* qrow = qbf + (size_t)(h * TT + qtok0 + lr) * 64 + lg * 8;
    bfrag aq0 = ldg8(qrow);
    bfrag aq1 = ldg8(qrow + 32);
    bfrag aq2 = {}, aq3 = {};
    if (isMid) {                       // rows qtok0+16.. only exist for mid
        const ushort* qrow1 = qrow + (size_t)16 * 64;
        aq2 = ldg8(qrow1);
        aq3 = ldg8(qrow1 + 32);
    }

    f32x4 zero = {0, 0, 0, 0};
    f32x4 o0[4] = {zero, zero, zero, zero};
    f32x4 o1[4] = {zero, zero, zero, zero};
    float l0[4] = {0.f, 0.f, 0.f, 0.f};
    float l1[4] = {0.f, 0.f, 0.f, 0.f};

    if (isMid) {
        int n = (qtok0 >> 6) - 1;
        int b0, b1;
        if (w == 0)      { b0 = 0;              b1 = NBLK - 1;       }
        else if (w == 1) { b0 = n;              b1 = n + 1;          }
        else if (w == 2) { b0 = n + 2;          b1 = rnd[n * 3 + 0]; }
        else             { b0 = rnd[n * 3 + 1]; b1 = rnd[n * 3 + 2]; }
        int kblk[2] = { b0, b1 };
        attn_core2x2(kbf, vT, mask, kblk, h, aq0, aq1, aq2, aq3,
                     &P[w][0], o0, o1, l0, l1);
    } else {
        int kb0[2] = { w * 4, w * 4 + 1 };
        attn_core2(kbf, vT, mask, kb0, h, aq0, aq1, &P[w][0], o0, l0);
        int kb1[2] = { w * 4 + 2, w * 4 + 3 };
        attn_core2(kbf, vT, mask, kb1, h, aq0, aq1, &P[w][0], o0, l0);
    }

    // wave-local row-sum reduces (over lr bits)
    #pragma unroll
    for (int j = 0; j < 4; j++) {
        float s0 = l0[j];
        s0 += __shfl_xor(s0, 1); s0 += __shfl_xor(s0, 2);
        s0 += __shfl_xor(s0, 4); s0 += __shfl_xor(s0, 8);
        l0[j] = s0;
        float s1 = l1[j];
        s1 += __shfl_xor(s1, 1); s1 += __shfl_xor(s1, 2);
        s1 += __shfl_xor(s1, 4); s1 += __shfl_xor(s1, 8);
        l1[j] = s1;
    }

    // ---- merge + write fragment 0 (rows qtok0 .. qtok0+15)
    #pragma unroll
    for (int dt = 0; dt < 4; dt++)
        #pragma unroll
        for (int j = 0; j < 4; j++)
            mo[w][dt][j][lane] = o0[dt][j];
    if (lr == 0) {
        #pragma unroll
        for (int j = 0; j < 4; j++) ml[w][lg * 4 + j] = l0[j];
    }
    __syncthreads();
    #pragma unroll
    for (int j = 0; j < 4; j++) {
        int row = lg * 4 + j;
        float lsum = ml[0][row] + ml[1][row] + ml[2][row] + ml[3][row];
        float of = mo[0][w][j][lane] + mo[1][w][j][lane] +
                   mo[2][w][j][lane] + mo[3][w][j][lane];
        ctx[(size_t)(qtok0 + row) * DD + h * 64 + w * 16 + lr] =
            f2bf(of / lsum);
    }

    if (!isMid) return;   // glob blocks have only 16 rows (block-uniform exit)

    __syncthreads();

    // ---- merge + write fragment 1 (rows qtok0+16 .. qtok0+31)
    #pragma unroll
    for (int dt = 0; dt < 4; dt++)
        #pragma unroll
        for (int j = 0; j < 4; j++)
            mo[w][dt][j][lane] = o1[dt][j];
    if (lr == 0) {
        #pragma unroll
        for (int j = 0; j < 4; j++) ml[w][lg * 4 + j] = l1[j];
    }
    __syncthreads();
    #pragma unroll
    for (int j = 0; j < 4; j++) {
        int row = lg * 4 + j;
        float lsum = ml[0][row] + ml[1][row] + ml[2][row] + ml[3][row];
        float of = mo[0][w][j][lane] + mo[1][w][j][lane] +
                   mo[2][w][j][lane] + mo[3][w][j][lane];
        ctx[(size_t)(qtok0 + 16 + row) * DD + h * 64 + w * 16 + lr] =
            f2bf(of / lsum);
    }
}

// ---------------------------------------------------------------------------
// Fused LayerNorm + final projection. One block per token. Wave-shfl stats,
// then 768x16 projection with coalesced Wc reads (kk = j*16+i partition).
// ---------------------------------------------------------------------------
__global__ __launch_bounds__(256) void ln_out_k(
    const float* __restrict__ hs, const float* __restrict__ g,
    const float* __restrict__ b, const float* __restrict__ Wc,
    const float* __restrict__ bc, float* __restrict__ out)
{
    int tk = blockIdx.x;
    int tid = threadIdx.x;
    int wv = tid >> 6, ln_ = tid & 63;
    __shared__ float ws[2][4];
    __shared__ float hsn[768];

    float x0 = hs[tk * DD + tid];
    float x1 = hs[tk * DD + tid + 256];
    float x2 = hs[tk * DD + tid + 512];

    float s = x0 + x1 + x2;
    float q = x0 * x0 + x1 * x1 + x2 * x2;
    #pragma unroll
    for (int off = 1; off < 64; off <<= 1) {
        s += __shfl_xor(s, off);
        q += __shfl_xor(q, off);
    }
    if (ln_ == 0) { ws[0][wv] = s; ws[1][wv] = q; }
    __syncthreads();
    float S = ws[0][0] + ws[0][1] + ws[0][2] + ws[0][3];
    float Q = ws[1][0] + ws[1][1] + ws[1][2] + ws[1][3];
    float mean = S * (1.0f / 768.0f);
    float var = Q * (1.0f / 768.0f) - mean * mean;
    float rstd = rsqrtf(var + 1e-12f);

    hsn[tid]       = (x0 - mean) * rstd * g[tid]       + b[tid];
    hsn[tid + 256] = (x1 - mean) * rstd * g[tid + 256] + b[tid + 256];
    hsn[tid + 512] = (x2 - mean) * rstd * g[tid + 512] + b[tid + 512];
    __syncthreads();

    // out projection: 16 cols x 16 threads/col, interleaved kk partition
    int c = tid >> 4, i = tid & 15;
    float acc = 0.0f;
    #pragma unroll 8
    for (int j = 0; j < 48; j++) {
        int kk = j * 16 + i;
        acc += hsn[kk] * Wc[kk * NCOUT + c];
    }
    acc += __shfl_xor(acc, 1); acc += __shfl_xor(acc, 2);
    acc += __shfl_xor(acc, 4); acc += __shfl_xor(acc, 8);
    if (i == 0) out[tk * NCOUT + c] = acc + bc[c];
}

// ---------------------------------------------------------------------------
extern "C" void kernel_launch(void* const* d_in, const int* in_sizes, int n_in,
                              void* d_out, int out_size, void* d_ws, size_t ws_size,
                              hipStream_t stream)
{
    const float* hidden = (const float*)d_in[0];
    const int*   mask   = (const int*)d_in[1];
    const int*   rnd    = (const int*)d_in[2];
    const float* Wq = (const float*)d_in[3];
    const float* bq = (const float*)d_in[4];
    const float* Wk = (const float*)d_in[5];
    const float* bk = (const float*)d_in[6];
    const float* Wv = (const float*)d_in[7];
    const float* bv = (const float*)d_in[8];
    const float* Wo = (const float*)d_in[9];
    const float* bo = (const float*)d_in[10];
    const float* Wd = (const float*)d_in[11];
    const float* bd = (const float*)d_in[12];
    const float* lng = (const float*)d_in[13];
    const float* lnb = (const float*)d_in[14];
    const float* Wc = (const float*)d_in[15];
    const float* bc = (const float*)d_in[16];
    float* out = (float*)d_out;

    // Only the LAST layer's hidden state reaches the output (out = hs[-1]).
    int L = in_sizes[0] / (TT * DD);
    const float* X = hidden + (size_t)(L - 1) * TT * DD;

    const size_t TD  = (size_t)TT * DD;     // 786432
    const size_t WSZ = (size_t)DD * DD;     // 589824

    ushort* xb   = (ushort*)d_ws;
    ushort* wqT  = xb   + TD;
    ushort* wkT  = wqT  + WSZ;
    ushort* wvT  = wkT  + WSZ;
    ushort* woT  = wvT  + WSZ;
    ushort* wdT  = woT  + WSZ;
    ushort* qbf  = wdT  + WSZ;
    ushort* kbf  = qbf  + TD;
    ushort* vTb  = kbf  + TD;
    ushort* ctxb = vTb  + TD;
    ushort* attb = ctxb + TD;
    float*  hs   = (float*)(attb + TD);

    prep_k<<<768 + 2880, 256, 0, stream>>>(X, Wq, Wk, Wv, Wo, Wd,
                                           xb, wqT, wkT, wvT, woT, wdT);
    qkv_mfma_k<<<dim3(16, NHEAD, 3), 256, 0, stream>>>(xb, wqT, wkT, wvT,
                                                       bq, bk, bv, qbf, kbf, vTb);
    attn_k<<<dim3(36, NHEAD), 256, 0, stream>>>(qbf, kbf, vTb, mask, rnd, ctxb);
    mm_mfma_k<0><<<dim3(32, NHEAD), 256, 0, stream>>>(ctxb, woT, bo, attb);
    mm_mfma_k<1><<<dim3(32, NHEAD), 256, 0, stream>>>(attb, wdT, bd, hs);
    ln_out_k<<<TT, 256, 0, stream>>>(hs, lng, lnb, Wc, bc, out);
}

// Round 20
// 92.802 us; speedup vs baseline: 1.0724x; 1.0724x over previous
//
#include <hip/hip_runtime.h>
#include <hip/hip_bf16.h>
#include <math.h>

#define TT    1024   // B*S tokens
#define DD    768    // hidden dim
#define NHEAD 12
#define HDIM  64
#define NBLK  16
#define NMID  14
#define NCOUT 16

typedef __attribute__((ext_vector_type(4))) float f32x4;
typedef __attribute__((ext_vector_type(8))) short bfrag;   // 8 bf16 = 4 VGPRs

#define MFMA(a, b, c) __builtin_amdgcn_mfma_f32_16x16x32_bf16(a, b, c, 0, 0, 0)

__device__ __forceinline__ bfrag ldg8(const ushort* p) { return *(const bfrag*)p; }
__device__ __forceinline__ ushort f2bf(float f) {
    __hip_bfloat16 h = __float2bfloat16(f);
    return *(ushort*)&h;
}

// ---------------------------------------------------------------------------
// Fused prep: blocks [0,768) convert X fp32->bf16; blocks [768, 768+2880)
// transpose+convert the 5 weight matrices W[k][n] -> WT[n][k] bf16.
// ---------------------------------------------------------------------------
__global__ __launch_bounds__(256) void prep_k(
    const float* __restrict__ X,
    const float* __restrict__ Wq, const float* __restrict__ Wk,
    const float* __restrict__ Wv, const float* __restrict__ Wo,
    const float* __restrict__ Wd,
    ushort* __restrict__ xb,
    ushort* __restrict__ qT, ushort* __restrict__ kT, ushort* __restrict__ vT,
    ushort* __restrict__ oT, ushort* __restrict__ dT)
{
    __shared__ float t[32][33];
    int bx = blockIdx.x;
    if (bx < 768) {                                  // X conversion
        int i = bx * 256 + threadIdx.x;              // float4 index
        float4 f = ((const float4*)X)[i];
        ushort4 u;
        u.x = f2bf(f.x); u.y = f2bf(f.y); u.z = f2bf(f.z); u.w = f2bf(f.w);
        ((ushort4*)xb)[i] = u;
        return;
    }
    int bz = bx - 768;                               // 0..2879
    int z = bz / 576;
    int rem = bz % 576;
    int k0 = (rem / 24) * 32, n0 = (rem % 24) * 32;
    const float* W; ushort* O;
    if (z == 0)      { W = Wq; O = qT; }
    else if (z == 1) { W = Wk; O = kT; }
    else if (z == 2) { W = Wv; O = vT; }
    else if (z == 3) { W = Wo; O = oT; }
    else             { W = Wd; O = dT; }
    int tx = threadIdx.x & 31, ty = threadIdx.x >> 5;   // ty 0..7
    #pragma unroll
    for (int i = 0; i < 4; i++)
        t[ty + i * 8][tx] = W[(k0 + ty + i * 8) * DD + n0 + tx];
    __syncthreads();
    #pragma unroll
    for (int i = 0; i < 4; i++)
        O[(n0 + ty + i * 8) * DD + k0 + tx] = f2bf(t[tx][ty + i * 8]);
}

// ---------------------------------------------------------------------------
// QKV MFMA GEMM, K-split, 64-row tiles (R13): grid (16, 12, 3).
// ---------------------------------------------------------------------------
__global__ __launch_bounds__(256) void qkv_mfma_k(
    const ushort* __restrict__ xb,
    const ushort* __restrict__ wqT, const ushort* __restrict__ wkT,
    const ushort* __restrict__ wvT,
    const float* __restrict__ bq, const float* __restrict__ bk,
    const float* __restrict__ bv,
    ushort* __restrict__ qo, ushort* __restrict__ ko, ushort* __restrict__ vTo)
{
    int z = blockIdx.z;
    const ushort* BT = (z == 0) ? wqT : (z == 1) ? wkT : wvT;
    const float* bias = (z == 0) ? bq : (z == 1) ? bk : bv;

    __shared__ float mo[4][16][4][64];   // [wave][m*4+nt][j][lane] = 64KB
    int lane = threadIdx.x & 63, w = threadIdx.x >> 6;
    int lr = lane & 15, lg = lane >> 4;
    int row0 = blockIdx.x * 64;
    int h = blockIdx.y;
    int col0 = h * 64;

    f32x4 acc[16];
    #pragma unroll
    for (int p = 0; p < 16; p++) acc[p] = (f32x4){0, 0, 0, 0};
    const ushort* ap = xb + (size_t)(row0 + lr) * DD + w * 192 + lg * 8;
    const ushort* bp = BT + (size_t)(col0 + lr) * DD + w * 192 + lg * 8;
    #pragma unroll
    for (int ks = 0; ks < 6; ks++) {
        bfrag a0 = ldg8(ap + ks * 32);
        bfrag a1 = ldg8(ap + (size_t)16 * DD + ks * 32);
        bfrag a2 = ldg8(ap + (size_t)32 * DD + ks * 32);
        bfrag a3 = ldg8(ap + (size_t)48 * DD + ks * 32);
        #pragma unroll
        for (int nt = 0; nt < 4; nt++) {
            bfrag b = ldg8(bp + (size_t)nt * 16 * DD + ks * 32);
            acc[nt]      = MFMA(a0, b, acc[nt]);
            acc[4 + nt]  = MFMA(a1, b, acc[4 + nt]);
            acc[8 + nt]  = MFMA(a2, b, acc[8 + nt]);
            acc[12 + nt] = MFMA(a3, b, acc[12 + nt]);
        }
    }
    #pragma unroll
    for (int p = 0; p < 16; p++)
        #pragma unroll
        for (int j = 0; j < 4; j++)
            mo[w][p][j][lane] = acc[p][j];
    __syncthreads();

    // wave w merges fragments p = w + 4*pi (pi 0..3)
    #pragma unroll
    for (int pi = 0; pi < 4; pi++) {
        int p = w + pi * 4;
        int m = p >> 2, nt = p & 3;
        #pragma unroll
        for (int j = 0; j < 4; j++) {
            float of = mo[0][p][j][lane] + mo[1][p][j][lane] +
                       mo[2][p][j][lane] + mo[3][p][j][lane];
            int r = row0 + m * 16 + lg * 4 + j;
            int cc = nt * 16 + lr;                 // col within head
            ushort u = f2bf(of + bias[col0 + cc]);
            if (z == 2)      vTo[(size_t)(h * 64 + cc) * TT + r] = u;
            else if (z == 0) qo[(size_t)(h * TT + r) * 64 + cc] = u;
            else             ko[(size_t)(h * TT + r) * 64 + cc] = u;
        }
    }
}

// ---------------------------------------------------------------------------
// Generic MFMA GEMM, K-split, 32-row tiles (R11-proven): grid (32,12).
// OUTF32=0 -> bf16 out, OUTF32=1 -> f32 out.
// ---------------------------------------------------------------------------
template <int OUTF32>
__global__ __launch_bounds__(256) void mm_mfma_k(
    const ushort* __restrict__ A, const ushort* __restrict__ BT,
    const float* __restrict__ bias, void* __restrict__ out)
{
    __shared__ float mo[4][8][4][64];   // [wave][m*4+nt][j][lane] = 32KB
    int lane = threadIdx.x & 63, w = threadIdx.x >> 6;
    int lr = lane & 15, lg = lane >> 4;
    int row0 = blockIdx.x * 32;
    int col0 = blockIdx.y * 64;

    f32x4 acc[8];
    #pragma unroll
    for (int p = 0; p < 8; p++) acc[p] = (f32x4){0, 0, 0, 0};
    const ushort* a0p = A + (size_t)(row0 + lr) * DD + w * 192 + lg * 8;
    const ushort* a1p = a0p + (size_t)16 * DD;
    const ushort* bp  = BT + (size_t)(col0 + lr) * DD + w * 192 + lg * 8;
    #pragma unroll
    for (int ks = 0; ks < 6; ks++) {
        bfrag a0 = ldg8(a0p + ks * 32);
        bfrag a1 = ldg8(a1p + ks * 32);
        #pragma unroll
        for (int nt = 0; nt < 4; nt++) {
            bfrag b = ldg8(bp + (size_t)nt * 16 * DD + ks * 32);
            acc[nt]     = MFMA(a0, b, acc[nt]);
            acc[4 + nt] = MFMA(a1, b, acc[4 + nt]);
        }
    }
    #pragma unroll
    for (int p = 0; p < 8; p++)
        #pragma unroll
        for (int j = 0; j < 4; j++)
            mo[w][p][j][lane] = acc[p][j];
    __syncthreads();

    // wave w merges fragment pairs p = w and p = w+4
    #pragma unroll
    for (int pi = 0; pi < 2; pi++) {
        int p = w + pi * 4;
        int m = p >> 2, nt = p & 3;
        #pragma unroll
        for (int j = 0; j < 4; j++) {
            float of = mo[0][p][j][lane] + mo[1][p][j][lane] +
                       mo[2][p][j][lane] + mo[3][p][j][lane];
            int r = row0 + m * 16 + lg * 4 + j;
            int c = col0 + nt * 16 + lr;
            float v = of + bias[c];
            if (OUTF32) ((float*)out)[(size_t)r * DD + c] = v;
            else        ((ushort*)out)[(size_t)r * DD + c] = f2bf(v);
        }
    }
}

// ---------------------------------------------------------------------------
// Attention wave core, 2 q-fragments (32 q-rows) vs 2 key blocks (128 keys).
// Each K-frag load feeds 2 QK MFMAs; each V-frag load feeds 8 PV MFMAs.
// P strips per (wave, frag): 2048 ushorts, swizzled.
// ---------------------------------------------------------------------------
__device__ __forceinline__ void attn_core2x2(
    const ushort* __restrict__ kbf, const ushort* __restrict__ vT,
    const int* __restrict__ mask, const int kblk[2], int h,
    bfrag aq0, bfrag aq1, bfrag aq2, bfrag aq3, ushort* __restrict__ Pw,
    f32x4 (&o0)[4], f32x4 (&o1)[4], float (&l0)[4], float (&l1)[4])
{
    int lane = threadIdx.x & 63, lr = lane & 15, lg = lane >> 4;
    #pragma unroll
    for (int kb = 0; kb < 2; kb++) {
        int bi = kblk[kb];
        #pragma unroll
        for (int kt = 0; kt < 4; kt++) {
            int key = bi * 64 + kt * 16 + lr;
            const ushort* krow = kbf + (size_t)(h * TT + key) * 64 + lg * 8;
            bfrag b0 = ldg8(krow);
            bfrag b1 = ldg8(krow + 32);
            f32x4 s0 = {0, 0, 0, 0}, s1 = {0, 0, 0, 0};
            s0 = MFMA(aq0, b0, s0); s0 = MFMA(aq1, b1, s0);
            s1 = MFMA(aq2, b0, s1); s1 = MFMA(aq3, b1, s1);
            int mk = mask[key];
            #pragma unroll
            for (int j = 0; j < 4; j++) {
                int row = lg * 4 + j;
                int base = (row * 128 + (kb * 4 + kt) * 16 + lr)
                           ^ ((row & 7) << 3);
                float p0 = (mk > 0) ? __expf(s0[j] * 0.125f) : 0.0f;
                l0[j] += p0;
                Pw[base] = f2bf(p0);
                float p1 = (mk > 0) ? __expf(s1[j] * 0.125f) : 0.0f;
                l1[j] += p1;
                Pw[2048 + base] = f2bf(p1);
            }
        }
    }
    #pragma unroll
    for (int ks = 0; ks < 4; ks++) {           // 32-key chunks
        int bi = kblk[ks >> 1];
        int pidx = (lr * 128 + ks * 32 + lg * 8) ^ ((lr & 7) << 3);
        bfrag pa0 = *(const bfrag*)(Pw + pidx);
        bfrag pa1 = *(const bfrag*)(Pw + 2048 + pidx);
        #pragma unroll
        for (int dt = 0; dt < 4; dt++) {
            const ushort* vrow = vT + (size_t)(h * 64 + dt * 16 + lr) * TT
                               + bi * 64 + (ks & 1) * 32 + lg * 8;
            bfrag vv = ldg8(vrow);
            o0[dt] = MFMA(pa0, vv, o0[dt]);
            o1[dt] = MFMA(pa1, vv, o1[dt]);
        }
    }
}

// ---------------------------------------------------------------------------
// Attention, k-split across waves, 32-row q-tiles, LOAD-BALANCED (R16).
// Grid (36, 12): x<28 -> mid tile (qb = 1+(x>>1), sub-half x&1, 8 gathered
// key blocks, 1 core call/wave). x>=28 -> glob tile split along keys: 2
// blocks per 32-row glob tile (z = key half), each 1 core call/wave, writing
// UNNORMALIZED fp32 partials (o, l) to pacc/pl (no-max softmax: partials
// merge by plain add). glob_comb_k merges + normalizes. All 432 blocks do
// identical work -> no straggler half.
// ---------------------------------------------------------------------------
__global__ __launch_bounds__(256, 3) void attn_k(
    const ushort* __restrict__ qbf, const ushort* __restrict__ kbf,
    const ushort* __restrict__ vT, const int* __restrict__ mask,
    const int* __restrict__ rnd, ushort* __restrict__ ctx,
    float* __restrict__ pacc, float* __restrict__ pl)
{
    __shared__ __align__(16) ushort P[4][4096];   // 32KB (2 frags per wave)
    __shared__ float mo[4][4][4][64];             // 16KB (reused per frag)
    __shared__ float ml[4][16];
    int x = blockIdx.x, h = blockIdx.y;
    int w = threadIdx.x >> 6, lane = threadIdx.x & 63;
    int lr = lane & 15, lg = lane >> 4;

    bool isMid = (x < 28);
    int qb, sub, g = 0, z = 0;
    if (isMid) { qb = 1 + (x >> 1); sub = x & 1; }
    else {
        int r = x - 28;               // 0..7
        g = r >> 2;                   // 0: qb0, 1: qb15
        sub = (r >> 1) & 1;           // which 32-row half
        z = r & 1;                    // key half: kb z*8 .. z*8+7
        qb = g ? (NBLK - 1) : 0;
    }
    int qtok0 = qb * 64 + sub * 32;

    const ushort* qrow = qbf + (size_t)(h * TT + qtok0 + lr) * 64 + lg * 8;
    bfrag aq0 = ldg8(qrow);
    bfrag aq1 = ldg8(qrow + 32);
    const ushort* qrow1 = qrow + (size_t)16 * 64;
    bfrag aq2 = ldg8(qrow1);
    bfrag aq3 = ldg8(qrow1 + 32);

    f32x4 zero = {0, 0, 0, 0};
    f32x4 o0[4] = {zero, zero, zero, zero};
    f32x4 o1[4] = {zero, zero, zero, zero};
    float l0[4] = {0.f, 0.f, 0.f, 0.f};
    float l1[4] = {0.f, 0.f, 0.f, 0.f};

    if (isMid) {
        int n = qb - 1;
        int b0, b1;
        if (w == 0)      { b0 = 0;              b1 = NBLK - 1;       }
        else if (w == 1) { b0 = n;              b1 = n + 1;          }
        else if (w == 2) { b0 = n + 2;          b1 = rnd[n * 3 + 0]; }
        else             { b0 = rnd[n * 3 + 1]; b1 = rnd[n * 3 + 2]; }
        int kblk[2] = { b0, b1 };
        attn_core2x2(kbf, vT, mask, kblk, h, aq0, aq1, aq2, aq3,
                     &P[w][0], o0, o1, l0, l1);
    } else {
        int kblk[2] = { z * 8 + w * 2, z * 8 + w * 2 + 1 };
        attn_core2x2(kbf, vT, mask, kblk, h, aq0, aq1, aq2, aq3,
                     &P[w][0], o0, o1, l0, l1);
    }

    // wave-local row-sum reduces (over lr bits)
    #pragma unroll
    for (int j = 0; j < 4; j++) {
        float s0 = l0[j];
        s0 += __shfl_xor(s0, 1); s0 += __shfl_xor(s0, 2);
        s0 += __shfl_xor(s0, 4); s0 += __shfl_xor(s0, 8);
        l0[j] = s0;
        float s1 = l1[j];
        s1 += __shfl_xor(s1, 1); s1 += __shfl_xor(s1, 2);
        s1 += __shfl_xor(s1, 4); s1 += __shfl_xor(s1, 8);
        l1[j] = s1;
    }

    int slot = ((g * 2 + sub) * 2 + z) * NHEAD + h;   // glob partial slot
    float* pb = pacc + (size_t)slot * 2048;           // [row32][col64]

    // ---- merge + write fragment 0 (rows qtok0 .. qtok0+15)
    #pragma unroll
    for (int dt = 0; dt < 4; dt++)
        #pragma unroll
        for (int j = 0; j < 4; j++)
            mo[w][dt][j][lane] = o0[dt][j];
    if (lr == 0) {
        #pragma unroll
        for (int j = 0; j < 4; j++) ml[w][lg * 4 + j] = l0[j];
    }
    __syncthreads();
    #pragma unroll
    for (int j = 0; j < 4; j++) {
        int row = lg * 4 + j;
        float lsum = ml[0][row] + ml[1][row] + ml[2][row] + ml[3][row];
        float of = mo[0][w][j][lane] + mo[1][w][j][lane] +
                   mo[2][w][j][lane] + mo[3][w][j][lane];
        if (isMid) {
            ctx[(size_t)(qtok0 + row) * DD + h * 64 + w * 16 + lr] =
                f2bf(of / lsum);
        } else {
            pb[row * 64 + w * 16 + lr] = of;
            if (w == 0 && lr == 0) pl[slot * 32 + row] = lsum;
        }
    }
    __syncthreads();

    // ---- merge + write fragment 1 (rows qtok0+16 .. qtok0+31)
    #pragma unroll
    for (int dt = 0; dt < 4; dt++)
        #pragma unroll
        for (int j = 0; j < 4; j++)
            mo[w][dt][j][lane] = o1[dt][j];
    if (lr == 0) {
        #pragma unroll
        for (int j = 0; j < 4; j++) ml[w][lg * 4 + j] = l1[j];
    }
    __syncthreads();
    #pragma unroll
    for (int j = 0; j < 4; j++) {
        int row = lg * 4 + j;
        float lsum = ml[0][row] + ml[1][row] + ml[2][row] + ml[3][row];
        float of = mo[0][w][j][lane] + mo[1][w][j][lane] +
                   mo[2][w][j][lane] + mo[3][w][j][lane];
        if (isMid) {
            ctx[(size_t)(qtok0 + 16 + row) * DD + h * 64 + w * 16 + lr] =
                f2bf(of / lsum);
        } else {
            pb[(16 + row) * 64 + w * 16 + lr] = of;
            if (w == 0 && lr == 0) pl[slot * 32 + 16 + row] = lsum;
        }
    }
}

// ---------------------------------------------------------------------------
// Merge the two key-half partials per glob 32-row tile, normalize, write ctx.
// Grid (4, 12): t = g*2+sub, h. 256 threads, 2048 elems (8 per thread).
// ---------------------------------------------------------------------------
__global__ __launch_bounds__(256) void glob_comb_k(
    const float* __restrict__ pacc, const float* __restrict__ pl,
    ushort* __restrict__ ctx)
{
    int t = blockIdx.x, h = blockIdx.y;
    int g = t >> 1, sub = t & 1;
    int qtok0 = (g ? (NBLK - 1) : 0) * 64 + sub * 32;
    int slot0 = (t * 2 + 0) * NHEAD + h;
    int slot1 = (t * 2 + 1) * NHEAD + h;
    const float* p0 = pacc + (size_t)slot0 * 2048;
    const float* p1 = pacc + (size_t)slot1 * 2048;
    int tid = threadIdx.x;
    #pragma unroll
    for (int it = 0; it < 8; it++) {
        int e = tid + it * 256;
        int r = e >> 6, c = e & 63;
        float l = pl[slot0 * 32 + r] + pl[slot1 * 32 + r];
        float v = (p0[e] + p1[e]) / l;
        ctx[(size_t)(qtok0 + r) * DD + h * 64 + c] = f2bf(v);
    }
}

// ---------------------------------------------------------------------------
// Fused LayerNorm + final projection. One block per token. Wave-shfl stats,
// then 768x16 projection with coalesced Wc reads (kk = j*16+i partition).
// ---------------------------------------------------------------------------
__global__ __launch_bounds__(256) void ln_out_k(
    const float* __restrict__ hs, const float* __restrict__ g,
    const float* __restrict__ b, const float* __restrict__ Wc,
    const float* __restrict__ bc, float* __restrict__ out)
{
    int tk = blockIdx.x;
    int tid = threadIdx.x;
    int wv = tid >> 6, ln_ = tid & 63;
    __shared__ float ws[2][4];
    __shared__ float hsn[768];

    float x0 = hs[tk * DD + tid];
    float x1 = hs[tk * DD + tid + 256];
    float x2 = hs[tk * DD + tid + 512];

    float s = x0 + x1 + x2;
    float q = x0 * x0 + x1 * x1 + x2 * x2;
    #pragma unroll
    for (int off = 1; off < 64; off <<= 1) {
        s += __shfl_xor(s, off);
        q += __shfl_xor(q, off);
    }
    if (ln_ == 0) { ws[0][wv] = s; ws[1][wv] = q; }
    __syncthreads();
    float S = ws[0][0] + ws[0][1] + ws[0][2] + ws[0][3];
    float Q = ws[1][0] + ws[1][1] + ws[1][2] + ws[1][3];
    float mean = S * (1.0f / 768.0f);
    float var = Q * (1.0f / 768.0f) - mean * mean;
    float rstd = rsqrtf(var + 1e-12f);

    hsn[tid]       = (x0 - mean) * rstd * g[tid]       + b[tid];
    hsn[tid + 256] = (x1 - mean) * rstd * g[tid + 256] + b[tid + 256];
    hsn[tid + 512] = (x2 - mean) * rstd * g[tid + 512] + b[tid + 512];
    __syncthreads();

    // out projection: 16 cols x 16 threads/col, interleaved kk partition
    int c = tid >> 4, i = tid & 15;
    float acc = 0.0f;
    #pragma unroll 8
    for (int j = 0; j < 48; j++) {
        int kk = j * 16 + i;
        acc += hsn[kk] * Wc[kk * NCOUT + c];
    }
    acc += __shfl_xor(acc, 1); acc += __shfl_xor(acc, 2);
    acc += __shfl_xor(acc, 4); acc += __shfl_xor(acc, 8);
    if (i == 0) out[tk * NCOUT + c] = acc + bc[c];
}

// ---------------------------------------------------------------------------
extern "C" void kernel_launch(void* const* d_in, const int* in_sizes, int n_in,
                              void* d_out, int out_size, void* d_ws, size_t ws_size,
                              hipStream_t stream)
{
    const float* hidden = (const float*)d_in[0];
    const int*   mask   = (const int*)d_in[1];
    const int*   rnd    = (const int*)d_in[2];
    const float* Wq = (const float*)d_in[3];
    const float* bq = (const float*)d_in[4];
    const float* Wk = (const float*)d_in[5];
    const float* bk = (const float*)d_in[6];
    const float* Wv = (const float*)d_in[7];
    const float* bv = (const float*)d_in[8];
    const float* Wo = (const float*)d_in[9];
    const float* bo = (const float*)d_in[10];
    const float* Wd = (const float*)d_in[11];
    const float* bd = (const float*)d_in[12];
    const float* lng = (const float*)d_in[13];
    const float* lnb = (const float*)d_in[14];
    const float* Wc = (const float*)d_in[15];
    const float* bc = (const float*)d_in[16];
    float* out = (float*)d_out;

    // Only the LAST layer's hidden state reaches the output (out = hs[-1]).
    int L = in_sizes[0] / (TT * DD);
    const float* X = hidden + (size_t)(L - 1) * TT * DD;

    const size_t TD  = (size_t)TT * DD;     // 786432
    const size_t WSZ = (size_t)DD * DD;     // 589824

    ushort* xb   = (ushort*)d_ws;
    ushort* wqT  = xb   + TD;
    ushort* wkT  = wqT  + WSZ;
    ushort* wvT  = wkT  + WSZ;
    ushort* woT  = wvT  + WSZ;
    ushort* wdT  = woT  + WSZ;
    ushort* qbf  = wdT  + WSZ;
    ushort* kbf  = qbf  + TD;
    ushort* vTb  = kbf  + TD;
    ushort* ctxb = vTb  + TD;
    ushort* attb = ctxb + TD;
    float*  hs   = (float*)(attb + TD);
    float*  pacc = hs + TD;                 // 96 slots * 2048 = 196608 floats
    float*  pl   = pacc + (size_t)96 * 2048;   // 96 * 32 = 3072 floats

    prep_k<<<768 + 2880, 256, 0, stream>>>(X, Wq, Wk, Wv, Wo, Wd,
                                           xb, wqT, wkT, wvT, woT, wdT);
    qkv_mfma_k<<<dim3(16, NHEAD, 3), 256, 0, stream>>>(xb, wqT, wkT, wvT,
                                                       bq, bk, bv, qbf, kbf, vTb);
    attn_k<<<dim3(36, NHEAD), 256, 0, stream>>>(qbf, kbf, vTb, mask, rnd,
                                                ctxb, pacc, pl);
    glob_comb_k<<<dim3(4, NHEAD), 256, 0, stream>>>(pacc, pl, ctxb);
    mm_mfma_k<0><<<dim3(32, NHEAD), 256, 0, stream>>>(ctxb, woT, bo, attb);
    mm_mfma_k<1><<<dim3(32, NHEAD), 256, 0, stream>>>(attb, wdT, bd, hs);
    ln_out_k<<<TT, 256, 0, stream>>>(hs, lng, lnb, Wc, bc, out);
}